// Round 1
// baseline (707.217 us; speedup 1.0000x reference)
//
#include <hip/hip_runtime.h>
#include <math.h>

#define BATCH 4
#define SEQ   1024
#define HID   512
#define NHEAD 8
#define DKH   64
#define NPOS  2047

// C[m][n] = sum_k A[m][k]*W[k][n] + bias[n]; optionally writes two outputs
// with per-column u/v biases added (for q_u / q_v). N=K=512 fixed.
// 64x64 tile, 256 threads, 4x4 micro-tile.
__global__ __launch_bounds__(256)
void gemm512(const float* __restrict__ A, const float* __restrict__ W,
             const float* __restrict__ bias,
             float* __restrict__ C0, float* __restrict__ C1,
             const float* __restrict__ ub, const float* __restrict__ vb,
             int M) {
  __shared__ float a_s[16][68];  // a_s[kk][i] = A[m0+i][k0+kk]
  __shared__ float w_s[16][68];  // w_s[kk][n] = W[k0+kk][n0+n]
  const int tid = threadIdx.x;
  const int m0 = blockIdx.y * 64, n0 = blockIdx.x * 64;
  const int ty = tid >> 4, tx = tid & 15;      // ty: row group, tx: col group
  const int lrow = tid >> 2, lc4 = (tid & 3) << 2;  // A-tile load map
  const int wkk = tid >> 4, wnc = (tid & 15) << 2;  // W-tile load map

  float acc[4][4] = {};
  for (int k0 = 0; k0 < 512; k0 += 16) {
    float4 av = make_float4(0.f, 0.f, 0.f, 0.f);
    if (m0 + lrow < M)
      av = *(const float4*)&A[(size_t)(m0 + lrow) * HID + k0 + lc4];
    float4 wv = *(const float4*)&W[(size_t)(k0 + wkk) * HID + n0 + wnc];
    __syncthreads();
    a_s[lc4 + 0][lrow] = av.x;
    a_s[lc4 + 1][lrow] = av.y;
    a_s[lc4 + 2][lrow] = av.z;
    a_s[lc4 + 3][lrow] = av.w;
    *(float4*)&w_s[wkk][wnc] = wv;
    __syncthreads();
#pragma unroll
    for (int kk = 0; kk < 16; ++kk) {
      float4 a4 = *(const float4*)&a_s[kk][ty << 2];
      float4 w4 = *(const float4*)&w_s[kk][tx << 2];
      float ar[4] = {a4.x, a4.y, a4.z, a4.w};
      float wr[4] = {w4.x, w4.y, w4.z, w4.w};
#pragma unroll
      for (int ii = 0; ii < 4; ++ii)
#pragma unroll
        for (int jj = 0; jj < 4; ++jj)
          acc[ii][jj] += ar[ii] * wr[jj];
    }
  }

  const int col = n0 + (tx << 2);
  float b4[4] = {bias[col], bias[col + 1], bias[col + 2], bias[col + 3]};
  float u4[4] = {0, 0, 0, 0}, v4[4] = {0, 0, 0, 0};
  if (C1) {
#pragma unroll
    for (int q = 0; q < 4; ++q) { u4[q] = ub[col + q]; v4[q] = vb[col + q]; }
  }
#pragma unroll
  for (int ii = 0; ii < 4; ++ii) {
    int row = m0 + (ty << 2) + ii;
    if (row < M) {
      size_t off = (size_t)row * HID + col;
      if (C1) {
        float4 r0, r1;
        r0.x = acc[ii][0] + b4[0] + u4[0];
        r0.y = acc[ii][1] + b4[1] + u4[1];
        r0.z = acc[ii][2] + b4[2] + u4[2];
        r0.w = acc[ii][3] + b4[3] + u4[3];
        r1.x = acc[ii][0] + b4[0] + v4[0];
        r1.y = acc[ii][1] + b4[1] + v4[1];
        r1.z = acc[ii][2] + b4[2] + v4[2];
        r1.w = acc[ii][3] + b4[3] + v4[3];
        *(float4*)&C0[off] = r0;
        *(float4*)&C1[off] = r1;
      } else {
        float4 r;
        r.x = acc[ii][0] + b4[0];
        r.y = acc[ii][1] + b4[1];
        r.z = acc[ii][2] + b4[2];
        r.w = acc[ii][3] + b4[3];
        *(float4*)&C0[off] = r;
      }
    }
  }
}

// Flash-style rel-pos attention, fp32.
// scores[t][j] = scale*(qu[t].k[j] + qv[t].p[SEQ-1-t+j]); softmax over j; out = attn@v.
// Block: one (b,h, 32-row q tile); 256 threads; j-tiles of 64.
__global__ __launch_bounds__(256)
void attn_fwd(const float* __restrict__ qu, const float* __restrict__ qvb,
              const float* __restrict__ kb, const float* __restrict__ vb,
              const float* __restrict__ pb, float* __restrict__ ob) {
  const int t0 = blockIdx.x * 32;
  const int h  = blockIdx.y;
  const int b  = blockIdx.z;
  const float scale = 0.125f;  // 1/sqrt(64)

  __shared__ float qu_s[32][68];
  __shared__ float qv_s[32][68];
  __shared__ float k_s[64][68];
  __shared__ float v_s[64][68];
  __shared__ float p_s[96][68];   // 95 rows used: rel window
  __shared__ float s_s[32][68];   // per-row scores (row fully inside one wave)

  const int tid = threadIdx.x;
  // stage q_u/q_v tiles (once)
  for (int idx = tid; idx < 32 * 16; idx += 256) {
    int i = idx >> 4, cc = (idx & 15) << 2;
    size_t g = (size_t)(b * SEQ + t0 + i) * HID + h * DKH + cc;
    *(float4*)&qu_s[i][cc] = *(const float4*)&qu[g];
    *(float4*)&qv_s[i][cc] = *(const float4*)&qvb[g];
  }

  const int i = tid >> 3;  // q-row within tile (0..31); row's 8 threads share a wave
  const int c = tid & 7;   // group (0..7)
  float m_run = -1e30f, l_run = 0.f;
  float o0[4] = {0, 0, 0, 0}, o1[4] = {0, 0, 0, 0};

  for (int j0 = 0; j0 < SEQ; j0 += 64) {
    __syncthreads();  // previous tile's reads done before overwrite
    // stage k/v tiles (64x64)
#pragma unroll
    for (int r = 0; r < 4; ++r) {
      int idx = tid + (r << 8);
      int jj = idx >> 4, cc = (idx & 15) << 2;
      size_t g = (size_t)(b * SEQ + j0 + jj) * HID + h * DKH + cc;
      *(float4*)&k_s[jj][cc] = *(const float4*)&kb[g];
      *(float4*)&v_s[jj][cc] = *(const float4*)&vb[g];
    }
    // stage p window: rows base..base+94; p_s row r <-> rel index base+r
    const int base = SEQ - 1 - t0 - 31 + j0;  // >= 0, base+94 <= 2046
    for (int idx = tid; idx < 95 * 16; idx += 256) {
      int rr = idx >> 4, cc = (idx & 15) << 2;
      *(float4*)&p_s[rr][cc] =
          *(const float4*)&pb[(size_t)(base + rr) * HID + h * DKH + cc];
    }
    __syncthreads();

    // scores: thread handles row i, columns jj = c + 8*s8 (stride-8 -> bank-clean)
    float sc[8] = {0, 0, 0, 0, 0, 0, 0, 0};
#pragma unroll
    for (int d0 = 0; d0 < 64; d0 += 4) {
      float4 u4 = *(const float4*)&qu_s[i][d0];
      float4 w4 = *(const float4*)&qv_s[i][d0];
#pragma unroll
      for (int s8 = 0; s8 < 8; ++s8) {
        int jj = c + (s8 << 3);
        float4 k4 = *(const float4*)&k_s[jj][d0];
        float4 p4 = *(const float4*)&p_s[jj + 31 - i][d0];
        sc[s8] += u4.x * k4.x + u4.y * k4.y + u4.z * k4.z + u4.w * k4.w +
                  w4.x * p4.x + w4.y * p4.y + w4.z * p4.z + w4.w * p4.w;
      }
    }
#pragma unroll
    for (int s8 = 0; s8 < 8; ++s8) s_s[i][c + (s8 << 3)] = sc[s8] * scale;
    // row lives in one wave: program order suffices, no block barrier needed
    float tm = -1e30f;
#pragma unroll
    for (int q0 = 0; q0 < 64; q0 += 4) {
      float4 s4 = *(const float4*)&s_s[i][q0];
      tm = fmaxf(tm, fmaxf(fmaxf(s4.x, s4.y), fmaxf(s4.z, s4.w)));
    }
    float m_new = fmaxf(m_run, tm);
    float corr = __expf(m_run - m_new);
    l_run *= corr;
#pragma unroll
    for (int q = 0; q < 4; ++q) { o0[q] *= corr; o1[q] *= corr; }
    // exponentiate own 8 columns, write back (same wave)
#pragma unroll
    for (int s8 = 0; s8 < 8; ++s8)
      s_s[i][c + (s8 << 3)] = __expf(sc[s8] * scale - m_new);
    // PV: thread accumulates out[i][c*8 .. c*8+7]
    float l_tile = 0.f;
#pragma unroll
    for (int q0 = 0; q0 < 64; q0 += 4) {
      float4 e4 = *(const float4*)&s_s[i][q0];
      l_tile += e4.x + e4.y + e4.z + e4.w;
      float er[4] = {e4.x, e4.y, e4.z, e4.w};
#pragma unroll
      for (int r = 0; r < 4; ++r) {
        float4 va = *(const float4*)&v_s[q0 + r][c << 3];
        float4 vb4 = *(const float4*)&v_s[q0 + r][(c << 3) + 4];
        o0[0] += er[r] * va.x;  o0[1] += er[r] * va.y;
        o0[2] += er[r] * va.z;  o0[3] += er[r] * va.w;
        o1[0] += er[r] * vb4.x; o1[1] += er[r] * vb4.y;
        o1[2] += er[r] * vb4.z; o1[3] += er[r] * vb4.w;
      }
    }
    l_run += l_tile;
    m_run = m_new;
  }

  const float inv = 1.f / l_run;
  size_t g = (size_t)(b * SEQ + t0 + i) * HID + h * DKH + (c << 3);
  float4 r0, r1;
  r0.x = o0[0] * inv; r0.y = o0[1] * inv; r0.z = o0[2] * inv; r0.w = o0[3] * inv;
  r1.x = o1[0] * inv; r1.y = o1[1] * inv; r1.z = o1[2] * inv; r1.w = o1[3] * inv;
  *(float4*)&ob[g] = r0;
  *(float4*)&ob[g + 4] = r1;
}

extern "C" void kernel_launch(void* const* d_in, const int* in_sizes, int n_in,
                              void* d_out, int out_size, void* d_ws, size_t ws_size,
                              hipStream_t stream) {
  const float* x   = (const float*)d_in[0];
  const float* pe  = (const float*)d_in[1];
  const float* Wq  = (const float*)d_in[2];
  const float* bq  = (const float*)d_in[3];
  const float* Wk  = (const float*)d_in[4];
  const float* bk  = (const float*)d_in[5];
  const float* Wv  = (const float*)d_in[6];
  const float* bv  = (const float*)d_in[7];
  const float* Wp  = (const float*)d_in[8];
  const float* bp  = (const float*)d_in[9];
  const float* Wo  = (const float*)d_in[10];
  const float* bo  = (const float*)d_in[11];
  const float* pbu = (const float*)d_in[12];
  const float* pbv = (const float*)d_in[13];
  float* out = (float*)d_out;
  float* ws  = (float*)d_ws;

  const size_t NTOK = (size_t)BATCH * SEQ;       // 4096
  float* qu = ws;
  float* qv = ws + 1 * NTOK * HID;
  float* kk = ws + 2 * NTOK * HID;
  float* vv = ws + 3 * NTOK * HID;
  float* ao = ws + 4 * NTOK * HID;
  float* pp = ws + 5 * NTOK * HID;               // 2047*512 floats

  dim3 blk(256);
  // projections
  gemm512<<<dim3(8, 64), blk, 0, stream>>>(x, Wq, bq, qu, qv, pbu, pbv, 4096);
  gemm512<<<dim3(8, 64), blk, 0, stream>>>(x, Wk, bk, kk, nullptr, nullptr, nullptr, 4096);
  gemm512<<<dim3(8, 64), blk, 0, stream>>>(x, Wv, bv, vv, nullptr, nullptr, nullptr, 4096);
  gemm512<<<dim3(8, 32), blk, 0, stream>>>(pe, Wp, bp, pp, nullptr, nullptr, nullptr, 2047);
  // attention
  attn_fwd<<<dim3(SEQ / 32, NHEAD, BATCH), blk, 0, stream>>>(qu, qv, kk, vv, pp, ao);
  // output projection
  gemm512<<<dim3(8, 64), blk, 0, stream>>>(ao, Wo, bo, out, nullptr, nullptr, nullptr, 4096);
}

// Round 2
// 130.164 us; speedup vs baseline: 5.4333x; 5.4333x over previous
//
#include <hip/hip_runtime.h>
#include <math.h>

#define BATCH 4
#define SEQ   1024
#define HID   512
#define NHEAD 8
#define DKH   64

typedef unsigned short u16;
typedef unsigned int   u32;
typedef short  short8 __attribute__((ext_vector_type(8)));
typedef float  f32x4  __attribute__((ext_vector_type(4)));

__device__ __forceinline__ u16 f2bf(float x) {
  u32 u = __builtin_bit_cast(u32, x);
  u32 r = (u + 0x7FFFu + ((u >> 16) & 1u)) >> 16;
  return (u16)r;
}
__device__ __forceinline__ float bf2f(u16 h) {
  u32 u = ((u32)h) << 16;
  return __builtin_bit_cast(float, u);
}

// ---------------- fp32 -> bf16 elementwise convert (vectorized) ----------------
__global__ __launch_bounds__(256)
void cvt_bf16(const float* __restrict__ s, u16* __restrict__ d, int n4) {
  int i = blockIdx.x * 256 + threadIdx.x;
  if (i < n4) {
    float4 v = *(const float4*)&s[(size_t)i * 4];
    ushort4 o;
    o.x = f2bf(v.x); o.y = f2bf(v.y); o.z = f2bf(v.z); o.w = f2bf(v.w);
    *(ushort4*)&d[(size_t)i * 4] = o;
  }
}

// ---------------- W (512x512 f32, k-major) -> Wt (n-major bf16), 5 mats --------
__global__ __launch_bounds__(256)
void transpose_w(const float* w0, const float* w1, const float* w2,
                 const float* w3, const float* w4, u16* __restrict__ wt) {
  const float* src;
  switch (blockIdx.z) {
    case 0: src = w0; break;
    case 1: src = w1; break;
    case 2: src = w2; break;
    case 3: src = w3; break;
    default: src = w4; break;
  }
  u16* dst = wt + (size_t)blockIdx.z * 512 * 512;
  __shared__ float t[32][33];
  const int tx = threadIdx.x, ty = threadIdx.y;  // block (32,8)
  const int k0 = blockIdx.x * 32, n0 = blockIdx.y * 32;
#pragma unroll
  for (int r = 0; r < 4; ++r)
    t[ty + 8 * r][tx] = src[(size_t)(k0 + ty + 8 * r) * 512 + n0 + tx];
  __syncthreads();
#pragma unroll
  for (int r = 0; r < 4; ++r)
    dst[(size_t)(n0 + ty + 8 * r) * 512 + k0 + tx] = f2bf(t[tx][ty + 8 * r]);
}

// ---------------- bf16 MFMA GEMM: C[MxN] = A[Mx512] @ Wt^T + bias --------------
// A bf16 row-major, Wt bf16 [N=512][K=512] (n-major). Tile BM=128,BN=64,BK=64.
// 256 thr = 4 waves (2x2), wave = 64x32 out = 4x2 frags of 16x16.
// MODE 0: bf16 out. MODE 1: dual bf16 out (+ub / +vb). MODE 2: bf16 transposed
// V-layout out [b][h][d][t]. MODE 3: f32 out.
template <int MODE>
__global__ __launch_bounds__(256)
void gemm_mfma(const u16* __restrict__ A, const u16* __restrict__ Bt,
               const float* __restrict__ bias,
               void* __restrict__ out0, void* __restrict__ out1,
               const float* __restrict__ ub, const float* __restrict__ vb,
               int M) {
  __shared__ u16 As[128 * 64];
  __shared__ u16 Bs[64 * 64];
  const int tid = threadIdx.x;
  const int m0 = blockIdx.y * 128, n0 = blockIdx.x * 64;
  const int wid = tid >> 6, lane = tid & 63;
  const int lr = lane & 15, lg = lane >> 4;
  const int wm = wid >> 1, wn = wid & 1;

  f32x4 acc[4][2];
#pragma unroll
  for (int i = 0; i < 4; ++i)
#pragma unroll
    for (int j = 0; j < 2; ++j) acc[i][j] = (f32x4)0.f;

  for (int kt = 0; kt < 8; ++kt) {
    const int k0 = kt * 64;
    short8 la[4], lb[2];
#pragma unroll
    for (int r = 0; r < 4; ++r) {
      int idx = tid + r * 256;            // 0..1023
      int arow = idx >> 3, ac = idx & 7;
      la[r] = (short8)0;
      if (m0 + arow < M)
        la[r] = *(const short8*)&A[(size_t)(m0 + arow) * 512 + k0 + ac * 8];
    }
#pragma unroll
    for (int r = 0; r < 2; ++r) {
      int idx = tid + r * 256;            // 0..511
      int brow = idx >> 3, bc = idx & 7;
      lb[r] = *(const short8*)&Bt[(size_t)(n0 + brow) * 512 + k0 + bc * 8];
    }
    __syncthreads();
#pragma unroll
    for (int r = 0; r < 4; ++r) {
      int idx = tid + r * 256;
      int arow = idx >> 3, ac = idx & 7;
      *(short8*)&As[arow * 64 + ((ac ^ (arow & 7)) * 8)] = la[r];
    }
#pragma unroll
    for (int r = 0; r < 2; ++r) {
      int idx = tid + r * 256;
      int brow = idx >> 3, bc = idx & 7;
      *(short8*)&Bs[brow * 64 + ((bc ^ (brow & 7)) * 8)] = lb[r];
    }
    __syncthreads();
#pragma unroll
    for (int kc = 0; kc < 2; ++kc) {
      const int ch = kc * 4 + lg;
      short8 af[4], bf[2];
#pragma unroll
      for (int mt = 0; mt < 4; ++mt) {
        int row = wm * 64 + mt * 16 + lr;
        af[mt] = *(const short8*)&As[row * 64 + ((ch ^ (row & 7)) * 8)];
      }
#pragma unroll
      for (int nt = 0; nt < 2; ++nt) {
        int nr = wn * 32 + nt * 16 + lr;
        bf[nt] = *(const short8*)&Bs[nr * 64 + ((ch ^ (nr & 7)) * 8)];
      }
#pragma unroll
      for (int mt = 0; mt < 4; ++mt)
#pragma unroll
        for (int nt = 0; nt < 2; ++nt)
          acc[mt][nt] = __builtin_amdgcn_mfma_f32_16x16x32_bf16(
              af[mt], bf[nt], acc[mt][nt], 0, 0, 0);
    }
    __syncthreads();
  }

  // epilogue
#pragma unroll
  for (int mt = 0; mt < 4; ++mt)
#pragma unroll
    for (int nt = 0; nt < 2; ++nt) {
      const int col = n0 + wn * 32 + nt * 16 + lr;
      const int rbase = m0 + wm * 64 + mt * 16 + lg * 4;
      const float b = bias[col];
      if (MODE == 2) {
        ushort4 pk;
        pk.x = f2bf(acc[mt][nt][0] + b);
        pk.y = f2bf(acc[mt][nt][1] + b);
        pk.z = f2bf(acc[mt][nt][2] + b);
        pk.w = f2bf(acc[mt][nt][3] + b);
        int bb = rbase >> 10, tl = rbase & 1023;
        u16* vt = (u16*)out0;
        *(ushort4*)&vt[(size_t)((bb * 8 + (col >> 6)) * 64 + (col & 63)) * 1024 + tl] = pk;
      } else {
#pragma unroll
        for (int q = 0; q < 4; ++q) {
          int row = rbase + q;
          if (row < M) {
            float v = acc[mt][nt][q] + b;
            if (MODE == 0) {
              ((u16*)out0)[(size_t)row * 512 + col] = f2bf(v);
            } else if (MODE == 1) {
              ((u16*)out0)[(size_t)row * 512 + col] = f2bf(v + ub[col]);
              ((u16*)out1)[(size_t)row * 512 + col] = f2bf(v + vb[col]);
            } else {
              ((float*)out0)[(size_t)row * 512 + col] = v;
            }
          }
        }
      }
    }
}

// ---------------- flash rel-pos attention, bf16 MFMA -------------------------
// block: (b, h, 64 q-rows). 4 waves, wave w owns rows t0+16w..+15.
// scores[t][j] = 0.125*(qu[t].k[j] + qv[t].p[1023-t+j]); online softmax; O=attn@V.
__global__ __launch_bounds__(256)
void attn_mfma(const u16* __restrict__ quP, const u16* __restrict__ qvP,
               const u16* __restrict__ kP, const u16* __restrict__ vtP,
               const u16* __restrict__ pP, u16* __restrict__ ao) {
  __shared__ u16 Ks[64 * 64];       // [j][d] swizzled
  __shared__ u16 Vs[64 * 64];       // [d][j] swizzled (V^T tile)
  __shared__ u16 Ps[128 * 64];      // [r][d] swizzled
  __shared__ float Bds[4][16][80];  // per-wave windowed Qv.P^T
  __shared__ u16 Es[4][16 * 64];    // per-wave exp(S) bf16, swizzled rows

  const int tid = threadIdx.x;
  const int wid = tid >> 6, lane = tid & 63;
  const int lr = lane & 15, lg = lane >> 4;
  const int t0 = blockIdx.x * 64, h = blockIdx.y, b = blockIdx.z;

  // Q fragments (A-layout: row=lr, k = kc*32 + lg*8 + 0..7)
  short8 aqu[2], aqv[2];
#pragma unroll
  for (int kc = 0; kc < 2; ++kc) {
    size_t g = (size_t)(b * SEQ + t0 + wid * 16 + lr) * 512 + h * 64 + kc * 32 + lg * 8;
    aqu[kc] = *(const short8*)&quP[g];
    aqv[kc] = *(const short8*)&qvP[g];
  }

  float mrun[4] = {-1e30f, -1e30f, -1e30f, -1e30f};
  float lrun[4] = {0.f, 0.f, 0.f, 0.f};
  f32x4 cO[4];
#pragma unroll
  for (int i = 0; i < 4; ++i) cO[i] = (f32x4)0.f;

  for (int j0 = 0; j0 < SEQ; j0 += 64) {
    // ---- stage K, V^T, P window ----
    short8 lk, lv, lp[4];
    {
      int row = tid >> 3, ch = tid & 7;  // wait: need 512 chunks for K with 256 thr
      // K: 64 rows x 8 chunks = 512; thread does 2 (tid, tid+256)
      (void)row; (void)ch;
    }
    short8 lk2, lv2;
    {
      int i0 = tid, i1 = tid + 256;
      int r0 = i0 >> 3, c0 = i0 & 7, r1 = i1 >> 3, c1 = i1 & 7;
      lk  = *(const short8*)&kP[(size_t)(b * SEQ + j0 + r0) * 512 + h * 64 + c0 * 8];
      lk2 = *(const short8*)&kP[(size_t)(b * SEQ + j0 + r1) * 512 + h * 64 + c1 * 8];
      lv  = *(const short8*)&vtP[(size_t)((b * 8 + h) * 64 + r0) * 1024 + j0 + c0 * 8];
      lv2 = *(const short8*)&vtP[(size_t)((b * 8 + h) * 64 + r1) * 1024 + j0 + c1 * 8];
      const int base = 960 - t0 + j0;
#pragma unroll
      for (int r = 0; r < 4; ++r) {
        int idx = tid + r * 256;
        int rr = idx >> 3, cc = idx & 7;
        lp[r] = *(const short8*)&pP[(size_t)(base + rr) * 512 + h * 64 + cc * 8];
      }
    }
    __syncthreads();
    {
      int i0 = tid, i1 = tid + 256;
      int r0 = i0 >> 3, c0 = i0 & 7, r1 = i1 >> 3, c1 = i1 & 7;
      *(short8*)&Ks[r0 * 64 + ((c0 ^ (r0 & 7)) * 8)] = lk;
      *(short8*)&Ks[r1 * 64 + ((c1 ^ (r1 & 7)) * 8)] = lk2;
      *(short8*)&Vs[r0 * 64 + ((c0 ^ (r0 & 7)) * 8)] = lv;
      *(short8*)&Vs[r1 * 64 + ((c1 ^ (r1 & 7)) * 8)] = lv2;
#pragma unroll
      for (int r = 0; r < 4; ++r) {
        int idx = tid + r * 256;
        int rr = idx >> 3, cc = idx & 7;
        *(short8*)&Ps[rr * 64 + ((cc ^ (rr & 7)) * 8)] = lp[r];
      }
    }
    __syncthreads();

    // ---- S_K = Qu @ K^T (4 n-tiles) ----
    f32x4 cK[4];
#pragma unroll
    for (int i = 0; i < 4; ++i) cK[i] = (f32x4)0.f;
#pragma unroll
    for (int kc = 0; kc < 2; ++kc) {
      const int ch = kc * 4 + lg;
#pragma unroll
      for (int nt = 0; nt < 4; ++nt) {
        int row = nt * 16 + lr;
        short8 bk = *(const short8*)&Ks[row * 64 + ((ch ^ (row & 7)) * 8)];
        cK[nt] = __builtin_amdgcn_mfma_f32_16x16x32_bf16(aqu[kc], bk, cK[nt], 0, 0, 0);
      }
    }
    // ---- Bd = Qv @ Pwin^T (5 n-tiles, window rows (3-w+pt)*16 ..) ----
    f32x4 cP[5];
#pragma unroll
    for (int i = 0; i < 5; ++i) cP[i] = (f32x4)0.f;
#pragma unroll
    for (int kc = 0; kc < 2; ++kc) {
      const int ch = kc * 4 + lg;
#pragma unroll
      for (int pt = 0; pt < 5; ++pt) {
        int row = (3 - wid + pt) * 16 + lr;
        short8 bp = *(const short8*)&Ps[row * 64 + ((ch ^ (row & 7)) * 8)];
        cP[pt] = __builtin_amdgcn_mfma_f32_16x16x32_bf16(aqv[kc], bp, cP[pt], 0, 0, 0);
      }
    }
    // write Bd to per-wave LDS: Bd[m][pt*16+lr]
#pragma unroll
    for (int pt = 0; pt < 5; ++pt)
#pragma unroll
      for (int q = 0; q < 4; ++q)
        Bds[wid][lg * 4 + q][pt * 16 + lr] = cP[pt][q];

    // ---- gather rel-shifted Bd, scale, softmax ----
    float s[4][4];  // [nt][q]
#pragma unroll
    for (int nt = 0; nt < 4; ++nt)
#pragma unroll
      for (int q = 0; q < 4; ++q) {
        int m = lg * 4 + q;
        int lrd = 15 - m + nt * 16 + lr;
        s[nt][q] = 0.125f * (cK[nt][q] + Bds[wid][m][lrd]);
      }
    float mnew[4], corr[4];
#pragma unroll
    for (int q = 0; q < 4; ++q) {
      float tm = fmaxf(fmaxf(s[0][q], s[1][q]), fmaxf(s[2][q], s[3][q]));
      tm = fmaxf(tm, __shfl_xor(tm, 1));
      tm = fmaxf(tm, __shfl_xor(tm, 2));
      tm = fmaxf(tm, __shfl_xor(tm, 4));
      tm = fmaxf(tm, __shfl_xor(tm, 8));
      mnew[q] = fmaxf(mrun[q], tm);
      corr[q] = __expf(mrun[q] - mnew[q]);
      lrun[q] *= corr[q];
      mrun[q] = mnew[q];
    }
#pragma unroll
    for (int nt = 0; nt < 4; ++nt) {
      f32x4 t = cO[nt];
      t[0] *= corr[0]; t[1] *= corr[1]; t[2] *= corr[2]; t[3] *= corr[3];
      cO[nt] = t;
    }
    // exp -> bf16 -> Es; accumulate row sums of quantized values
    float psum[4] = {0.f, 0.f, 0.f, 0.f};
#pragma unroll
    for (int nt = 0; nt < 4; ++nt)
#pragma unroll
      for (int q = 0; q < 4; ++q) {
        int m = lg * 4 + q;
        int jp = nt * 16 + lr;
        u16 eh = f2bf(__expf(s[nt][q] - mnew[q]));
        psum[q] += bf2f(eh);
        Es[wid][m * 64 + (((jp >> 3) ^ (m & 7)) * 8) + (jp & 7)] = eh;
      }
#pragma unroll
    for (int q = 0; q < 4; ++q) {
      float ps = psum[q];
      ps += __shfl_xor(ps, 1);
      ps += __shfl_xor(ps, 2);
      ps += __shfl_xor(ps, 4);
      ps += __shfl_xor(ps, 8);
      lrun[q] += ps;
    }
    // ---- O += E @ V ----
#pragma unroll
    for (int kc = 0; kc < 2; ++kc) {
      const int ch = kc * 4 + lg;
      short8 ae = *(const short8*)&Es[wid][lr * 64 + ((ch ^ (lr & 7)) * 8)];
#pragma unroll
      for (int nt = 0; nt < 4; ++nt) {
        int vr = nt * 16 + lr;
        short8 bv = *(const short8*)&Vs[vr * 64 + ((ch ^ (vr & 7)) * 8)];
        cO[nt] = __builtin_amdgcn_mfma_f32_16x16x32_bf16(ae, bv, cO[nt], 0, 0, 0);
      }
    }
    __syncthreads();
  }

  float inv[4];
#pragma unroll
  for (int q = 0; q < 4; ++q) inv[q] = 1.f / lrun[q];
#pragma unroll
  for (int nt = 0; nt < 4; ++nt)
#pragma unroll
    for (int q = 0; q < 4; ++q) {
      int row = b * SEQ + t0 + wid * 16 + lg * 4 + q;
      ao[(size_t)row * 512 + h * 64 + nt * 16 + lr] = f2bf(cO[nt][q] * inv[q]);
    }
}

extern "C" void kernel_launch(void* const* d_in, const int* in_sizes, int n_in,
                              void* d_out, int out_size, void* d_ws, size_t ws_size,
                              hipStream_t stream) {
  const float* x   = (const float*)d_in[0];
  const float* pe  = (const float*)d_in[1];
  const float* Wq  = (const float*)d_in[2];
  const float* bq  = (const float*)d_in[3];
  const float* Wk  = (const float*)d_in[4];
  const float* bk  = (const float*)d_in[5];
  const float* Wv  = (const float*)d_in[6];
  const float* bv  = (const float*)d_in[7];
  const float* Wp  = (const float*)d_in[8];
  const float* bp  = (const float*)d_in[9];
  const float* Wo  = (const float*)d_in[10];
  const float* bo  = (const float*)d_in[11];
  const float* pbu = (const float*)d_in[12];
  const float* pbv = (const float*)d_in[13];

  char* ws = (char*)d_ws;
  size_t o = 0;
  auto alloc = [&](size_t bytes) { size_t r = o; o += (bytes + 255) & ~(size_t)255; return r; };
  u16* x_bf  = (u16*)(ws + alloc((size_t)4096 * 512 * 2));
  u16* pe_bf = (u16*)(ws + alloc((size_t)2048 * 512 * 2));
  u16* wt    = (u16*)(ws + alloc((size_t)5 * 512 * 512 * 2));
  u16* qu    = (u16*)(ws + alloc((size_t)4096 * 512 * 2));
  u16* qv    = (u16*)(ws + alloc((size_t)4096 * 512 * 2));
  u16* kk    = (u16*)(ws + alloc((size_t)4096 * 512 * 2));
  u16* vt    = (u16*)(ws + alloc((size_t)4096 * 512 * 2));
  u16* pp    = (u16*)(ws + alloc((size_t)2048 * 512 * 2));
  u16* ao    = (u16*)(ws + alloc((size_t)4096 * 512 * 2));

  dim3 blk(256);
  // converts
  cvt_bf16<<<dim3((4096 * 512 / 4 + 255) / 256), blk, 0, stream>>>(x, x_bf, 4096 * 512 / 4);
  cvt_bf16<<<dim3((2047 * 512 / 4 + 255) / 256), blk, 0, stream>>>(pe, pe_bf, 2047 * 512 / 4);
  transpose_w<<<dim3(16, 16, 5), dim3(32, 8), 0, stream>>>(Wq, Wk, Wv, Wp, Wo, wt);
  // zero the padding row of pp (row 2047) so staging reads are clean
  hipMemsetAsync(pp + (size_t)2047 * 512, 0, 512 * 2, stream);

  // projections
  gemm_mfma<1><<<dim3(8, 32), blk, 0, stream>>>(x_bf, wt + 0 * 512 * 512, bq, qu, qv, pbu, pbv, 4096);
  gemm_mfma<0><<<dim3(8, 32), blk, 0, stream>>>(x_bf, wt + 1 * 512 * 512, bk, kk, nullptr, nullptr, nullptr, 4096);
  gemm_mfma<2><<<dim3(8, 32), blk, 0, stream>>>(x_bf, wt + 2 * 512 * 512, bv, vt, nullptr, nullptr, nullptr, 4096);
  gemm_mfma<0><<<dim3(8, 16), blk, 0, stream>>>(pe_bf, wt + 3 * 512 * 512, bp, pp, nullptr, nullptr, nullptr, 2047);
  // attention
  attn_mfma<<<dim3(16, NHEAD, BATCH), blk, 0, stream>>>(qu, qv, kk, vt, pp, ao);
  // output projection (f32 out)
  gemm_mfma<3><<<dim3(8, 32), blk, 0, stream>>>(ao, wt + 4 * 512 * 512, bo, d_out, nullptr, nullptr, nullptr, 4096);
}

// Round 4
// 115.089 us; speedup vs baseline: 6.1450x; 1.1310x over previous
//
#include <hip/hip_runtime.h>
#include <math.h>

#define BATCH 4
#define SEQ   1024
#define HID   512
#define NHEAD 8

typedef unsigned short u16;
typedef unsigned int   u32;
typedef short  short8 __attribute__((ext_vector_type(8)));
typedef float  f32x4  __attribute__((ext_vector_type(4)));

__device__ __forceinline__ u16 f2bf(float x) {
  u32 u = __builtin_bit_cast(u32, x);
  u32 r = (u + 0x7FFFu + ((u >> 16) & 1u)) >> 16;
  return (u16)r;
}
__device__ __forceinline__ float bf2f(u16 h) {
  u32 u = ((u32)h) << 16;
  return __builtin_bit_cast(float, u);
}

// ---------------- fp32 -> bf16 convert ----------------
__global__ __launch_bounds__(256)
void cvt_bf16(const float* __restrict__ s, u16* __restrict__ d, int n4) {
  int i = blockIdx.x * 256 + threadIdx.x;
  if (i < n4) {
    float4 v = *(const float4*)&s[(size_t)i * 4];
    ushort4 o;
    o.x = f2bf(v.x); o.y = f2bf(v.y); o.z = f2bf(v.z); o.w = f2bf(v.w);
    *(ushort4*)&d[(size_t)i * 4] = o;
  }
}

// ---------------- W (512x512 f32 k-major) -> Wt (n-major bf16), 5 mats -------
__global__ __launch_bounds__(256)
void transpose_w(const float* w0, const float* w1, const float* w2,
                 const float* w3, const float* w4, u16* __restrict__ wt) {
  const float* src;
  switch (blockIdx.z) {
    case 0: src = w0; break;
    case 1: src = w1; break;
    case 2: src = w2; break;
    case 3: src = w3; break;
    default: src = w4; break;
  }
  u16* dst = wt + (size_t)blockIdx.z * 512 * 512;
  __shared__ float t[32][33];
  const int tx = threadIdx.x, ty = threadIdx.y;  // block (32,8)
  const int k0 = blockIdx.x * 32, n0 = blockIdx.y * 32;
#pragma unroll
  for (int r = 0; r < 4; ++r)
    t[ty + 8 * r][tx] = src[(size_t)(k0 + ty + 8 * r) * 512 + n0 + tx];
  __syncthreads();
#pragma unroll
  for (int r = 0; r < 4; ++r)
    dst[(size_t)(n0 + ty + 8 * r) * 512 + k0 + tx] = f2bf(t[tx][ty + 8 * r]);
}

// ---------------- MFMA GEMM core: acc = A[BMx512] @ Bt^T tile ---------------
// MF=4 -> BM=128; MF=2 -> BM=64. BN=128, BK=64. 4 waves (2x2).
// Register-staged loads + XOR-swizzled ds_write (verified round-2 mechanism).
template <int MF>
__device__ __forceinline__ void gemm_core(const u16* __restrict__ A,
                                          const u16* __restrict__ Bt,
                                          int m0, int n0, u16* As, u16* Bs,
                                          f32x4 (&acc)[MF][4]) {
  const int tid = threadIdx.x;
  const int wid = tid >> 6, lane = tid & 63;
  const int lr = lane & 15, lg = lane >> 4;
  const int wm = wid >> 1, wn = wid & 1;
  const int srow = tid >> 3, sc = tid & 7;  // staging row base / chunk
#pragma unroll
  for (int i = 0; i < MF; ++i)
#pragma unroll
    for (int j = 0; j < 4; ++j) acc[i][j] = (f32x4)0.f;

  for (int kt = 0; kt < 8; ++kt) {
    const int k0 = kt * 64;
    short8 la[MF], lb[4];
#pragma unroll
    for (int r = 0; r < MF; ++r)
      la[r] = *(const short8*)&A[(size_t)(m0 + srow + 32 * r) * 512 + k0 + sc * 8];
#pragma unroll
    for (int r = 0; r < 4; ++r)
      lb[r] = *(const short8*)&Bt[(size_t)(n0 + srow + 32 * r) * 512 + k0 + sc * 8];
    __syncthreads();
#pragma unroll
    for (int r = 0; r < MF; ++r) {
      int row = srow + 32 * r;
      *(short8*)&As[row * 64 + ((sc ^ (row & 7)) * 8)] = la[r];
    }
#pragma unroll
    for (int r = 0; r < 4; ++r) {
      int row = srow + 32 * r;
      *(short8*)&Bs[row * 64 + ((sc ^ (row & 7)) * 8)] = lb[r];
    }
    __syncthreads();
#pragma unroll
    for (int kc = 0; kc < 2; ++kc) {
      const int ch = kc * 4 + lg;
      short8 af[MF], bfr[4];
#pragma unroll
      for (int mt = 0; mt < MF; ++mt) {
        int row = wm * (MF * 16) + mt * 16 + lr;
        af[mt] = *(const short8*)&As[row * 64 + ((ch ^ (row & 7)) * 8)];
      }
#pragma unroll
      for (int nt = 0; nt < 4; ++nt) {
        int row = wn * 64 + nt * 16 + lr;
        bfr[nt] = *(const short8*)&Bs[row * 64 + ((ch ^ (row & 7)) * 8)];
      }
#pragma unroll
      for (int mt = 0; mt < MF; ++mt)
#pragma unroll
        for (int nt = 0; nt < 4; ++nt)
          acc[mt][nt] = __builtin_amdgcn_mfma_f32_16x16x32_bf16(
              af[mt], bfr[nt], acc[mt][nt], 0, 0, 0);
    }
  }
}

// ---------------- fused Q/K/V/P projection GEMM (z = 0..3) ------------------
__global__ __launch_bounds__(256)
void gemm_qkvp(const u16* __restrict__ xbf, const u16* __restrict__ pebf,
               const u16* __restrict__ wt,
               const float* __restrict__ bq, const float* __restrict__ bk,
               const float* __restrict__ bv, const float* __restrict__ bp,
               const float* __restrict__ pbu, const float* __restrict__ pbv,
               u16* __restrict__ qu, u16* __restrict__ qv,
               u16* __restrict__ kk, u16* __restrict__ vt,
               u16* __restrict__ pp) {
  __shared__ __align__(16) u16 As[128 * 64];
  __shared__ __align__(16) u16 Bs[128 * 64];
  const int z = blockIdx.z;
  if (z == 3 && blockIdx.y >= 16) return;
  const u16* A = (z == 3) ? pebf : xbf;
  const u16* Bt = wt + (size_t)z * 512 * 512;
  const float* bias = (z == 0) ? bq : (z == 1) ? bk : (z == 2) ? bv : bp;
  const int m0 = blockIdx.y * 128, n0 = blockIdx.x * 128;

  f32x4 acc[4][4];
  gemm_core<4>(A, Bt, m0, n0, As, Bs, acc);

  const int tid = threadIdx.x, wid = tid >> 6, lane = tid & 63;
  const int lr = lane & 15, lg = lane >> 4, wm = wid >> 1, wn = wid & 1;
#pragma unroll
  for (int mt = 0; mt < 4; ++mt)
#pragma unroll
    for (int nt = 0; nt < 4; ++nt) {
      const int col = n0 + wn * 64 + nt * 16 + lr;
      const int rb = m0 + wm * 64 + mt * 16 + lg * 4;
      const float bcol = bias[col];
      if (z == 0) {
        const float uu = pbu[col], vv = pbv[col];
#pragma unroll
        for (int q = 0; q < 4; ++q) {
          float val = acc[mt][nt][q] + bcol;
          qu[(size_t)(rb + q) * 512 + col] = f2bf(val + uu);
          qv[(size_t)(rb + q) * 512 + col] = f2bf(val + vv);
        }
      } else if (z == 1) {
#pragma unroll
        for (int q = 0; q < 4; ++q)
          kk[(size_t)(rb + q) * 512 + col] = f2bf(acc[mt][nt][q] + bcol);
      } else if (z == 2) {
        // V^T layout [b][h][d][t]
        ushort4 pk;
        pk.x = f2bf(acc[mt][nt][0] + bcol);
        pk.y = f2bf(acc[mt][nt][1] + bcol);
        pk.z = f2bf(acc[mt][nt][2] + bcol);
        pk.w = f2bf(acc[mt][nt][3] + bcol);
        int bb = rb >> 10, tl = rb & 1023;
        *(ushort4*)&vt[(size_t)((bb * 8 + (col >> 6)) * 64 + (col & 63)) * 1024 + tl] = pk;
      } else {
#pragma unroll
        for (int q = 0; q < 4; ++q)
          if (rb + q < 2047)
            pp[(size_t)(rb + q) * 512 + col] = f2bf(acc[mt][nt][q] + bcol);
      }
    }
}

// ---------------- output projection: out = ao @ Wo^T + bo (f32) -------------
__global__ __launch_bounds__(256)
void gemm_wo(const u16* __restrict__ ao, const u16* __restrict__ wt,
             const float* __restrict__ bo, float* __restrict__ out) {
  __shared__ __align__(16) u16 As[64 * 64];
  __shared__ __align__(16) u16 Bs[128 * 64];
  const int m0 = blockIdx.y * 64, n0 = blockIdx.x * 128;
  f32x4 acc[2][4];
  gemm_core<2>(ao, wt + (size_t)4 * 512 * 512, m0, n0, As, Bs, acc);
  const int tid = threadIdx.x, wid = tid >> 6, lane = tid & 63;
  const int lr = lane & 15, lg = lane >> 4, wm = wid >> 1, wn = wid & 1;
#pragma unroll
  for (int mt = 0; mt < 2; ++mt)
#pragma unroll
    for (int nt = 0; nt < 4; ++nt) {
      const int col = n0 + wn * 64 + nt * 16 + lr;
      const int rb = m0 + wm * 32 + mt * 16 + lg * 4;
      const float bcol = bo[col];
#pragma unroll
      for (int q = 0; q < 4; ++q)
        out[(size_t)(rb + q) * 512 + col] = acc[mt][nt][q] + bcol;
    }
}

// ---------------- flash rel-pos attention, bf16 MFMA -------------------------
// block: (b, h, 64 q-rows). 4 waves, wave w owns rows t0+16w..+15.
// scores[t][j] = 0.125*(qu[t].k[j] + qv[t].p[1023-t+j]); online softmax; O=attn@V.
__global__ __launch_bounds__(256)
void attn_mfma(const u16* __restrict__ quP, const u16* __restrict__ qvP,
               const u16* __restrict__ kP, const u16* __restrict__ vtP,
               const u16* __restrict__ pP, u16* __restrict__ ao) {
  __shared__ __align__(16) u16 Ks[64 * 64];     // [j][d] swz
  __shared__ __align__(16) u16 Vs[64 * 64];     // [d][j] swz (V^T tile)
  __shared__ __align__(16) u16 Ps[128 * 64];    // [r][d] swz
  __shared__ __align__(16) u16 Es[4][16 * 64];  // per-wave exp(S) bf16, swz

  const int tid = threadIdx.x;
  const int wid = tid >> 6, lane = tid & 63;
  const int lr = lane & 15, lg = lane >> 4;
  const int srow = tid >> 3, sc = tid & 7;
  const int t0 = blockIdx.x * 64, h = blockIdx.y, b = blockIdx.z;

  short8 aqu[2], aqv[2];
#pragma unroll
  for (int kc = 0; kc < 2; ++kc) {
    size_t g = (size_t)(b * SEQ + t0 + wid * 16 + lr) * 512 + h * 64 + kc * 32 + lg * 8;
    aqu[kc] = *(const short8*)&quP[g];
    aqv[kc] = *(const short8*)&qvP[g];
  }

  float mrun[4] = {-1e30f, -1e30f, -1e30f, -1e30f};
  float lrun[4] = {0.f, 0.f, 0.f, 0.f};
  f32x4 cO[4];
#pragma unroll
  for (int i = 0; i < 4; ++i) cO[i] = (f32x4)0.f;

  u16* esw = &Es[wid][0];

  for (int j0 = 0; j0 < SEQ; j0 += 64) {
    const int base = 960 - t0 + j0;  // window start, >=0, +127 <= 2047
    short8 lk[2], lv[2], lp[4];
#pragma unroll
    for (int r = 0; r < 2; ++r) {
      int row = srow + 32 * r;
      lk[r] = *(const short8*)&kP[(size_t)(b * SEQ + j0 + row) * 512 + h * 64 + sc * 8];
      lv[r] = *(const short8*)&vtP[(size_t)((b * 8 + h) * 64 + row) * 1024 + j0 + sc * 8];
    }
#pragma unroll
    for (int r = 0; r < 4; ++r) {
      int row = srow + 32 * r;
      lp[r] = *(const short8*)&pP[(size_t)(base + row) * 512 + h * 64 + sc * 8];
    }
    __syncthreads();  // previous tile's reads done before overwrite
#pragma unroll
    for (int r = 0; r < 2; ++r) {
      int row = srow + 32 * r;
      *(short8*)&Ks[row * 64 + ((sc ^ (row & 7)) * 8)] = lk[r];
      *(short8*)&Vs[row * 64 + ((sc ^ (row & 7)) * 8)] = lv[r];
    }
#pragma unroll
    for (int r = 0; r < 4; ++r) {
      int row = srow + 32 * r;
      *(short8*)&Ps[row * 64 + ((sc ^ (row & 7)) * 8)] = lp[r];
    }
    __syncthreads();

    // ---- S_K = Qu @ K^T ; windowed Bd = Qv @ P^T ----
    f32x4 cK[4], cP5[5];
#pragma unroll
    for (int i = 0; i < 4; ++i) cK[i] = (f32x4)0.f;
#pragma unroll
    for (int i = 0; i < 5; ++i) cP5[i] = (f32x4)0.f;
#pragma unroll
    for (int kc = 0; kc < 2; ++kc) {
      const int ch = kc * 4 + lg;
#pragma unroll
      for (int nt = 0; nt < 4; ++nt) {
        int row = nt * 16 + lr;
        short8 bk = *(const short8*)&Ks[row * 64 + ((ch ^ (row & 7)) * 8)];
        cK[nt] = __builtin_amdgcn_mfma_f32_16x16x32_bf16(aqu[kc], bk, cK[nt], 0, 0, 0);
      }
#pragma unroll
      for (int pt = 0; pt < 5; ++pt) {
        int row = (3 - wid + pt) * 16 + lr;
        short8 bp = *(const short8*)&Ps[row * 64 + ((ch ^ (row & 7)) * 8)];
        cP5[pt] = __builtin_amdgcn_mfma_f32_16x16x32_bf16(aqv[kc], bp, cP5[pt], 0, 0, 0);
      }
    }

    // ---- rel-shift gather via shuffle: row m needs window col nt*16 + u, u = lr+15-m
    float s[4][4];
#pragma unroll
    for (int q = 0; q < 4; ++q) {
      int u = lr + 15 - lg * 4 - q;            // 0..30
      int src = (lane & 48) | (u & 15);
      float sh[5];
#pragma unroll
      for (int pt = 0; pt < 5; ++pt) sh[pt] = __shfl(cP5[pt][q], src, 64);
      bool hi = (u & 16) != 0;
#pragma unroll
      for (int nt = 0; nt < 4; ++nt) {
        float bd = hi ? sh[nt + 1] : sh[nt];
        s[nt][q] = 0.125f * (cK[nt][q] + bd);
      }
    }

    // ---- online softmax with defer-max (THR=8) ----
    float pm[4];
#pragma unroll
    for (int q = 0; q < 4; ++q) {
      float tm = fmaxf(fmaxf(s[0][q], s[1][q]), fmaxf(s[2][q], s[3][q]));
      tm = fmaxf(tm, __shfl_xor(tm, 1));
      tm = fmaxf(tm, __shfl_xor(tm, 2));
      tm = fmaxf(tm, __shfl_xor(tm, 4));
      tm = fmaxf(tm, __shfl_xor(tm, 8));
      pm[q] = tm;
    }
    int need = 0;
#pragma unroll
    for (int q = 0; q < 4; ++q) need |= (pm[q] > mrun[q] + 8.f) ? 1 : 0;
    if (__any(need)) {
#pragma unroll
      for (int q = 0; q < 4; ++q) {
        float mnew = fmaxf(mrun[q], pm[q]);
        float corr = __expf(mrun[q] - mnew);
        lrun[q] *= corr;
        mrun[q] = mnew;
#pragma unroll
        for (int nt = 0; nt < 4; ++nt) cO[nt][q] *= corr;
      }
    }

    // ---- exp -> bf16, store Es, accumulate quantized row sums ----
    float ps[4] = {0.f, 0.f, 0.f, 0.f};
#pragma unroll
    for (int nt = 0; nt < 4; ++nt) {
      int jp = nt * 16 + lr, sw = jp >> 3, jb = jp & 7;
#pragma unroll
      for (int q = 0; q < 4; ++q) {
        int m = lg * 4 + q;
        u16 eh = f2bf(__expf(s[nt][q] - mrun[q]));
        ps[q] += bf2f(eh);
        esw[m * 64 + ((sw ^ (m & 7)) * 8) + jb] = eh;
      }
    }
#pragma unroll
    for (int q = 0; q < 4; ++q) {
      float v = ps[q];
      v += __shfl_xor(v, 1);
      v += __shfl_xor(v, 2);
      v += __shfl_xor(v, 4);
      v += __shfl_xor(v, 8);
      lrun[q] += v;
    }

    // ---- O += E @ V ----
#pragma unroll
    for (int kc = 0; kc < 2; ++kc) {
      const int ch = kc * 4 + lg;
      short8 ae = *(const short8*)&esw[lr * 64 + ((ch ^ (lr & 7)) * 8)];
#pragma unroll
      for (int nt = 0; nt < 4; ++nt) {
        int vr = nt * 16 + lr;
        short8 bv = *(const short8*)&Vs[vr * 64 + ((ch ^ (vr & 7)) * 8)];
        cO[nt] = __builtin_amdgcn_mfma_f32_16x16x32_bf16(ae, bv, cO[nt], 0, 0, 0);
      }
    }
    __syncthreads();
  }

  float inv[4];
#pragma unroll
  for (int q = 0; q < 4; ++q) inv[q] = 1.f / lrun[q];
#pragma unroll
  for (int nt = 0; nt < 4; ++nt)
#pragma unroll
    for (int q = 0; q < 4; ++q) {
      int row = b * SEQ + t0 + wid * 16 + lg * 4 + q;
      ao[(size_t)row * 512 + h * 64 + nt * 16 + lr] = f2bf(cO[nt][q] * inv[q]);
    }
}

extern "C" void kernel_launch(void* const* d_in, const int* in_sizes, int n_in,
                              void* d_out, int out_size, void* d_ws, size_t ws_size,
                              hipStream_t stream) {
  const float* x   = (const float*)d_in[0];
  const float* pe  = (const float*)d_in[1];
  const float* Wq  = (const float*)d_in[2];
  const float* bq  = (const float*)d_in[3];
  const float* Wk  = (const float*)d_in[4];
  const float* bk  = (const float*)d_in[5];
  const float* Wv  = (const float*)d_in[6];
  const float* bv  = (const float*)d_in[7];
  const float* Wp  = (const float*)d_in[8];
  const float* bp  = (const float*)d_in[9];
  const float* Wo  = (const float*)d_in[10];
  const float* bo  = (const float*)d_in[11];
  const float* pbu = (const float*)d_in[12];
  const float* pbv = (const float*)d_in[13];

  char* ws = (char*)d_ws;
  size_t o = 0;
  auto alloc = [&](size_t bytes) { size_t r = o; o += (bytes + 255) & ~(size_t)255; return r; };
  u16* x_bf  = (u16*)(ws + alloc((size_t)4096 * 512 * 2));
  u16* pe_bf = (u16*)(ws + alloc((size_t)2048 * 512 * 2));
  u16* wt    = (u16*)(ws + alloc((size_t)5 * 512 * 512 * 2));
  u16* qu    = (u16*)(ws + alloc((size_t)4096 * 512 * 2));
  u16* qv    = (u16*)(ws + alloc((size_t)4096 * 512 * 2));
  u16* kk    = (u16*)(ws + alloc((size_t)4096 * 512 * 2));
  u16* vt    = (u16*)(ws + alloc((size_t)4096 * 512 * 2));
  u16* pp    = (u16*)(ws + alloc((size_t)2048 * 512 * 2));
  u16* ao    = (u16*)(ws + alloc((size_t)4096 * 512 * 2));

  dim3 blk(256);
  cvt_bf16<<<dim3(2048), blk, 0, stream>>>(x, x_bf, 4096 * 512 / 4);
  cvt_bf16<<<dim3(1024), blk, 0, stream>>>(pe, pe_bf, 2047 * 512 / 4);
  transpose_w<<<dim3(16, 16, 5), dim3(32, 8), 0, stream>>>(Wq, Wk, Wv, Wp, Wo, wt);
  hipMemsetAsync(pp + (size_t)2047 * 512, 0, 512 * 2, stream);

  gemm_qkvp<<<dim3(4, 32, 4), blk, 0, stream>>>(x_bf, pe_bf, wt, bq, bk, bv, bp,
                                                pbu, pbv, qu, qv, kk, vt, pp);
  attn_mfma<<<dim3(16, NHEAD, BATCH), blk, 0, stream>>>(qu, qv, kk, vt, pp, ao);
  gemm_wo<<<dim3(4, 64), blk, 0, stream>>>(ao, wt, bo, (float*)d_out);
}